// Round 1
// baseline (201.444 us; speedup 1.0000x reference)
//
#include <hip/hip_runtime.h>

// ---------------------------------------------------------------------------
// CMHSAttn: 1x1-conv QKV projection + 8-head self-attention, N=4096, d_head=16
// x: (128, 4096) bf16 (assumed; runtime-probed), W: (384, 128) bf16
// qkv[o,n] = sum_c W[o,c] x[c,n]; per head h: q=rows 48h..+16, k=+16, v=+32
// scores = (1/sqrt(128)) Q^T K ; softmax over keys ; out[16h+d, n]
// ---------------------------------------------------------------------------

typedef __attribute__((ext_vector_type(4))) float  f32x4;
typedef __attribute__((ext_vector_type(8))) short  s16x8;
typedef __attribute__((ext_vector_type(4))) short  s16x4;
typedef __attribute__((ext_vector_type(8))) __bf16 bf16x8;

union FragAB { s16x8 s; bf16x8 b; };

__device__ __forceinline__ float bf2f(short v) {
    return __uint_as_float(((unsigned)(unsigned short)v) << 16);
}
__device__ __forceinline__ short f2bf(float f) {
    unsigned u = __float_as_uint(f);
    u += 0x7fff + ((u >> 16) & 1);          // RNE
    return (short)(u >> 16);
}

#define SCALE 0.08838834764831845f   // 1/sqrt(128) -- note: d_model, not d_head

// ---------------------------------------------------------------------------
// dtype probe: lower 16 bits of W dwords are a plausible bf16 value only if
// the buffer is genuinely bf16 (fp32 low mantissa bits -> random exponent).
// ---------------------------------------------------------------------------
__global__ void detect_kernel(const unsigned* __restrict__ w_raw, int* __restrict__ flag) {
    __shared__ int tot;
    int tid = threadIdx.x;
    if (tid == 0) tot = 0;
    __syncthreads();
    int cnt = 0;
    for (int i = tid; i < 1024; i += 256) {
        float v = fabsf(__uint_as_float((w_raw[i] & 0xffffu) << 16));
        if (v >= 1e-3f && v <= 4.0f) cnt++;
    }
    atomicAdd(&tot, cnt);
    __syncthreads();
    if (tid == 0) *flag = (tot >= 512) ? 1 : 0;   // 1 => bf16 inputs/outputs
}

// ---------------------------------------------------------------------------
// QKV projection: tile 128 o x 64 n, c=128 full. grid (3, 64), 256 threads.
// ---------------------------------------------------------------------------
__global__ __launch_bounds__(256) void qkv_kernel(const void* __restrict__ x_in,
                                                  const void* __restrict__ w_in,
                                                  short* __restrict__ qkv,
                                                  const int* __restrict__ flag)
{
    const int o0 = blockIdx.x * 128;
    const int n0 = blockIdx.y * 64;
    __shared__ __align__(16) short sX[128][64];    // [c][n]
    __shared__ __align__(16) short sWt[128][128];  // [c][o]  (transposed)
    const int tid = threadIdx.x;
    const int is_bf16 = *flag;

    if (is_bf16) {
        const short* x = (const short*)x_in;
        const short* w = (const short*)w_in;
        #pragma unroll
        for (int kk = 0; kk < 4; ++kk) {
            int j = tid + kk * 256;             // 1024 chunks of 8
            int c = j >> 3;
            int m = (j & 7) * 8;
            *(s16x8*)&sX[c][m] = *(const s16x8*)&x[c * 4096 + n0 + m];
        }
        #pragma unroll
        for (int kk = 0; kk < 8; ++kk) {
            int j = tid + kk * 256;             // 2048 chunks of 8
            int o = j >> 4;
            int c = (j & 15) * 8;
            s16x8 wv = *(const s16x8*)&w[(o0 + o) * 128 + c];
            #pragma unroll
            for (int t = 0; t < 8; ++t) sWt[c + t][o] = wv[t];
        }
    } else {
        const float* x = (const float*)x_in;
        const float* w = (const float*)w_in;
        #pragma unroll
        for (int kk = 0; kk < 4; ++kk) {
            int j = tid + kk * 256;
            int c = j >> 3;
            int m = (j & 7) * 8;
            f32x4 a = *(const f32x4*)&x[c * 4096 + n0 + m];
            f32x4 b = *(const f32x4*)&x[c * 4096 + n0 + m + 4];
            s16x8 pk;
            #pragma unroll
            for (int t = 0; t < 4; ++t) { pk[t] = f2bf(a[t]); pk[t + 4] = f2bf(b[t]); }
            *(s16x8*)&sX[c][m] = pk;
        }
        #pragma unroll
        for (int kk = 0; kk < 8; ++kk) {
            int j = tid + kk * 256;
            int o = j >> 4;
            int c = (j & 15) * 8;
            f32x4 a = *(const f32x4*)&w[(o0 + o) * 128 + c];
            f32x4 b = *(const f32x4*)&w[(o0 + o) * 128 + c + 4];
            #pragma unroll
            for (int t = 0; t < 4; ++t) { sWt[c + t][o] = f2bf(a[t]); sWt[c + 4 + t][o] = f2bf(b[t]); }
        }
    }
    __syncthreads();

    const int tx = tid & 15;   // n micro (4 cols)
    const int ty = tid >> 4;   // o micro (8 rows)
    float acc[8][4];
    #pragma unroll
    for (int i = 0; i < 8; ++i)
        #pragma unroll
        for (int t = 0; t < 4; ++t) acc[i][t] = 0.f;

    for (int c = 0; c < 128; ++c) {
        s16x4 xr = *(const s16x4*)&sX[c][tx * 4];
        float xv[4];
        #pragma unroll
        for (int t = 0; t < 4; ++t) xv[t] = bf2f(xr[t]);
        s16x8 wr = *(const s16x8*)&sWt[c][ty * 8];
        #pragma unroll
        for (int i = 0; i < 8; ++i) {
            float wf = bf2f(wr[i]);
            #pragma unroll
            for (int t = 0; t < 4; ++t) acc[i][t] = fmaf(wf, xv[t], acc[i][t]);
        }
    }
    #pragma unroll
    for (int i = 0; i < 8; ++i) {
        s16x4 pk;
        #pragma unroll
        for (int t = 0; t < 4; ++t) pk[t] = f2bf(acc[i][t]);
        *(s16x4*)&qkv[(o0 + ty * 8 + i) * 4096 + n0 + tx * 4] = pk;
    }
}

// ---------------------------------------------------------------------------
// Flash attention. block = 256 thr = 4 waves; wave owns 16 q rows.
// grid = 8 heads * 64 q-tiles = 512 blocks. Key tiles of 64.
// MFMA 16x16x32 bf16; d_head=16 -> upper K-half zeroed for QK^T.
// ---------------------------------------------------------------------------
__global__ __launch_bounds__(256) void attn_kernel(const short* __restrict__ qkv,
                                                   void* __restrict__ out_v,
                                                   const int* __restrict__ flag)
{
    const int head = blockIdx.x >> 6;
    const int qt   = blockIdx.x & 63;
    const int tid  = threadIdx.x;
    const int wave = tid >> 6;
    const int lane = tid & 63;
    const int col  = lane & 15;
    const int quad = lane >> 4;

    __shared__ __align__(16) short sKt[64][24];    // [m][d] transposed, padded
    __shared__ __align__(16) short sV[16][72];     // [d][m] padded
    __shared__ __align__(16) short sP[4][16][72];  // [wave][qrow][m] padded

    const short* qbase = qkv + (head * 48) * 4096;
    const short* kbase = qkv + (head * 48 + 16) * 4096;
    const short* vbase = qkv + (head * 48 + 32) * 4096;

    const int q0 = qt * 64 + wave * 16;

    // Q A-fragment: A[m=col][k=quad*8+j], k = d (0..15), zeros for k>=16
    FragAB qf; qf.s = 0;
    if (quad < 2) {
        #pragma unroll
        for (int j = 0; j < 8; ++j)
            qf.s[j] = qbase[(quad * 8 + j) * 4096 + q0 + col];
    }

    f32x4 o_acc = {0.f, 0.f, 0.f, 0.f};
    float m_row[4], l_row[4];
    #pragma unroll
    for (int r = 0; r < 4; ++r) { m_row[r] = -1e30f; l_row[r] = 0.f; }

    for (int kt = 0; kt < 64; ++kt) {
        const int m0 = kt * 64;
        __syncthreads();                 // previous iter done with sKt/sV
        {
            int i = tid * 4;
            int d = i >> 6, mm = i & 63;
            s16x4 kv = *(const s16x4*)&kbase[d * 4096 + m0 + mm];
            s16x4 vv = *(const s16x4*)&vbase[d * 4096 + m0 + mm];
            #pragma unroll
            for (int j = 0; j < 4; ++j) sKt[mm + j][d] = kv[j];
            *(s16x4*)&sV[d][mm] = vv;
        }
        __syncthreads();

        // scores: 4 subtiles of 16 keys; C-layout: row=quad*4+r, key=t*16+col
        f32x4 s[4];
        #pragma unroll
        for (int t = 0; t < 4; ++t) {
            FragAB kf; kf.s = 0;
            if (quad < 2) kf.s = *(const s16x8*)&sKt[t * 16 + col][quad * 8];
            f32x4 z = {0.f, 0.f, 0.f, 0.f};
            s[t] = __builtin_amdgcn_mfma_f32_16x16x32_bf16(qf.b, kf.b, z, 0, 0, 0);
        }
        #pragma unroll
        for (int t = 0; t < 4; ++t)
            #pragma unroll
            for (int r = 0; r < 4; ++r) s[t][r] *= SCALE;

        // online softmax per row (row-wise reduce across the 16-lane group)
        #pragma unroll
        for (int r = 0; r < 4; ++r) {
            float mx = fmaxf(fmaxf(s[0][r], s[1][r]), fmaxf(s[2][r], s[3][r]));
            #pragma unroll
            for (int off = 8; off >= 1; off >>= 1)
                mx = fmaxf(mx, __shfl_xor(mx, off, 64));
            float mnew = fmaxf(m_row[r], mx);
            float al = __expf(m_row[r] - mnew);
            m_row[r] = mnew;
            float rs = 0.f;
            #pragma unroll
            for (int t = 0; t < 4; ++t) {
                float p = __expf(s[t][r] - mnew);
                short pb = f2bf(p);
                sP[wave][quad * 4 + r][t * 16 + col] = pb;
                rs += bf2f(pb);          // use rounded value for consistency
            }
            #pragma unroll
            for (int off = 8; off >= 1; off >>= 1)
                rs += __shfl_xor(rs, off, 64);
            l_row[r] = l_row[r] * al + rs;
            o_acc[r] *= al;              // rescale BEFORE PV accumulation
        }

        // PV: A = P (A-layout from LDS), B[k=m][n=d] = sV[d][m]; K=64 -> 2 MFMAs
        #pragma unroll
        for (int c = 0; c < 2; ++c) {
            FragAB pf, vf;
            pf.s = *(const s16x8*)&sP[wave][col][c * 32 + quad * 8];
            vf.s = *(const s16x8*)&sV[col][c * 32 + quad * 8];
            o_acc = __builtin_amdgcn_mfma_f32_16x16x32_bf16(pf.b, vf.b, o_acc, 0, 0, 0);
        }
    }

    // epilogue: out[(16*head + d)*4096 + n], d=col, n=q0+quad*4+r (4 consecutive)
    const long ob = (long)(head * 16 + col) * 4096 + q0 + quad * 4;
    if (*flag) {
        short* out = (short*)out_v;
        s16x4 res;
        #pragma unroll
        for (int r = 0; r < 4; ++r) res[r] = f2bf(o_acc[r] / l_row[r]);
        *(s16x4*)&out[ob] = res;
    } else {
        float* out = (float*)out_v;
        f32x4 res;
        #pragma unroll
        for (int r = 0; r < 4; ++r) res[r] = o_acc[r] / l_row[r];
        *(f32x4*)&out[ob] = res;
    }
}

// ---------------------------------------------------------------------------
extern "C" void kernel_launch(void* const* d_in, const int* in_sizes, int n_in,
                              void* d_out, int out_size, void* d_ws, size_t ws_size,
                              hipStream_t stream) {
    const void* x = d_in[0];       // (128, 4096)
    const void* w = d_in[1];       // (384, 128)
    int*   flag = (int*)d_ws;
    short* qkv  = (short*)((char*)d_ws + 256);   // 384*4096 bf16 = 3 MB

    detect_kernel<<<1, 256, 0, stream>>>((const unsigned*)w, flag);
    dim3 g1(3, 64);
    qkv_kernel<<<g1, 256, 0, stream>>>(x, w, qkv, flag);
    attn_kernel<<<512, 256, 0, stream>>>(qkv, d_out, flag);
}

// Round 5
// 143.614 us; speedup vs baseline: 1.4027x; 1.4027x over previous
//
#include <hip/hip_runtime.h>

// ---------------------------------------------------------------------------
// CMHSAttn v4: fp32 in/out (R3/R4 NaN forensics: fp32 read as bf16 -> inf/NaN;
// reference dtype is float32 and R1 passed via its fp32 probe path).
//   qkv_kernel: fp32 x,W -> bf16 inline -> MFMA GEMM (384x4096x128)
//               -> qT[h][n][16] (scale*log2e folded), kT[h][n][16], v[h][16][n]
//               (all bf16 in workspace)
//   attn_kernel: zero-LDS flash attention, S^T orientation, max-free softmax
//               (st clamped -> NaN-proof), split-K x4 fp32 partials
//   combine_kernel: sum partials, divide, fp32 store
// ---------------------------------------------------------------------------

typedef __attribute__((ext_vector_type(4))) float  f32x4;
typedef __attribute__((ext_vector_type(8))) short  s16x8;
typedef __attribute__((ext_vector_type(4))) short  s16x4;
typedef __attribute__((ext_vector_type(8))) __bf16 bf16x8;

union FragAB { s16x8 s; bf16x8 b; };

__device__ __forceinline__ short f2bf(float f) {
    unsigned u = __float_as_uint(f);
    u += 0x7fff + ((u >> 16) & 1);          // RNE
    return (short)(u >> 16);
}

#define SL2E 0.12751744154070513f   // (1/sqrt(128)) * log2(e)

// ---------------------------------------------------------------------------
// QKV: A = W-frag (fp32 load + cvt), B = X^T-frag (LDS-staged bf16).
// grid (64 n-tiles of 64, 4 o-quarters of 96), 256 thr. Wave = 16 n x 96 o.
// ---------------------------------------------------------------------------
__global__ __launch_bounds__(256) void qkv_kernel(
    const float* __restrict__ x, const float* __restrict__ w,
    short* __restrict__ qT, short* __restrict__ kT, short* __restrict__ v)
{
    __shared__ __align__(16) short xT[4][16][136];   // [wave][n][c], pad 8
    const int wv   = threadIdx.x >> 6;
    const int lane = threadIdx.x & 63;
    const int colL = lane & 15, quad = lane >> 4;
    const int n0 = blockIdx.x * 64 + wv * 16;
    const int oq = blockIdx.y;                        // 0..3

    // stage X^T slice: 16 n x 128 c per wave (fp32 -> bf16)
    #pragma unroll
    for (int rr = 0; rr < 4; ++rr) {
        int c  = rr * 32 + (lane >> 1);
        int nh = (lane & 1) * 8;
        f32x4 a = *(const f32x4*)&x[c * 4096 + n0 + nh];
        f32x4 b = *(const f32x4*)&x[c * 4096 + n0 + nh + 4];
        #pragma unroll
        for (int t = 0; t < 4; ++t) {
            xT[wv][nh + t][c]     = f2bf(a[t]);
            xT[wv][nh + 4 + t][c] = f2bf(b[t]);
        }
    }
    __syncthreads();

    FragAB xb[4];
    #pragma unroll
    for (int ks = 0; ks < 4; ++ks)
        xb[ks].s = *(const s16x8*)&xT[wv][colL][ks * 32 + quad * 8];

    #pragma unroll
    for (int i = 0; i < 6; ++i) {
        const int otg  = oq * 6 + i;          // global 16-o tile, 0..23
        const int ob   = otg * 16;
        const int h    = otg / 3;
        const int kind = otg % 3;             // 0=q, 1=k, 2=v
        f32x4 acc = {0.f, 0.f, 0.f, 0.f};
        #pragma unroll
        for (int ks = 0; ks < 4; ++ks) {
            f32x4 wa0 = *(const f32x4*)&w[(ob + colL) * 128 + ks * 32 + quad * 8];
            f32x4 wa1 = *(const f32x4*)&w[(ob + colL) * 128 + ks * 32 + quad * 8 + 4];
            FragAB wa;
            #pragma unroll
            for (int t = 0; t < 4; ++t) {
                wa.s[t]     = f2bf(wa0[t]);
                wa.s[t + 4] = f2bf(wa1[t]);
            }
            acc = __builtin_amdgcn_mfma_f32_16x16x32_bf16(wa.b, xb[ks].b, acc, 0, 0, 0);
        }
        // C: row = o_local = quad*4+r, col = n = n0+colL
        if (kind == 2) {
            #pragma unroll
            for (int r = 0; r < 4; ++r)
                v[(h * 16 + quad * 4 + r) * 4096 + n0 + colL] = f2bf(acc[r]);
        } else {
            short* dst = (kind == 0) ? qT : kT;
            const float sc = (kind == 0) ? SL2E : 1.0f;
            s16x4 pk;
            #pragma unroll
            for (int r = 0; r < 4; ++r) pk[r] = f2bf(acc[r] * sc);
            *(s16x4*)&dst[(h * 4096 + n0 + colL) * 16 + quad * 4] = pk;
        }
    }
}

// ---------------------------------------------------------------------------
// Attention. Wave = 16 q rows x key chunk. Block = 4 waves. No LDS/barriers.
// S^T = K*Q^T: st[t][r] = score[key = m0+t*16+quad*4+r][q = q0+colL].
// PV: A = V (m=d), B = P^T with k-slot (quad,j) -> key m0+c*32+(j<4?0:16)
//     +quad*4+(j&3) -- exactly the lane's own st values.
// ---------------------------------------------------------------------------
template<int SPLIT>
__global__ __launch_bounds__(256) void attn_kernel(
    const short* __restrict__ qT, const short* __restrict__ kT,
    const short* __restrict__ v,
    float* __restrict__ Opart, float* __restrict__ lpart,
    float* __restrict__ out)
{
    const int wv   = threadIdx.x >> 6;
    const int lane = threadIdx.x & 63;
    const int colL = lane & 15, quad = lane >> 4;

    const int bx = blockIdx.x;
    int s, h, qt4;
    if (SPLIT > 1) { s = bx >> 9; h = (bx >> 6) & 7; qt4 = bx & 63; }
    else           { s = 0;       h = bx >> 6;       qt4 = bx & 63; }
    const int q0  = qt4 * 64 + wv * 16;
    const int nkt = 64 / SPLIT;

    const short* qb = qT + (h * 4096 + q0) * 16;
    const short* kb = kT +  h * 4096 * 16;
    const short* vb = v  +  h * 16 * 4096;

    FragAB qf; qf.s = 0;                       // B-frag: Q^T[d][q], d<16
    if (quad < 2) qf.s = *(const s16x8*)&qb[colL * 16 + quad * 8];

    f32x4 o_acc = {0.f, 0.f, 0.f, 0.f};        // C: row=d, col=q
    float l0 = 0.f, l1 = 0.f;

    const int kt_base = s * nkt;
    for (int kt = 0; kt < nkt; ++kt) {
        const int m0 = (kt_base + kt) * 64;

        FragAB kf[4];                           // A-frag: K[key][d], d<16
        #pragma unroll
        for (int t = 0; t < 4; ++t) {
            kf[t].s = 0;
            if (quad < 2)
                kf[t].s = *(const s16x8*)&kb[(m0 + t * 16 + colL) * 16 + quad * 8];
        }
        f32x4 st[4];
        #pragma unroll
        for (int t = 0; t < 4; ++t) {
            f32x4 z = {0.f, 0.f, 0.f, 0.f};
            st[t] = __builtin_amdgcn_mfma_f32_16x16x32_bf16(kf[t].b, qf.b, z, 0, 0, 0);
        }

        // exp2 (scale folded into qT); clamp => finite everywhere, l > 0
        short pv[4][4];
        #pragma unroll
        for (int t = 0; t < 4; ++t) {
            #pragma unroll
            for (int r = 0; r < 4; ++r) {
                float sv = fminf(fmaxf(st[t][r], -30.f), 60.f);
                float p  = exp2f(sv);
                if (r & 1) l1 += p; else l0 += p;
                pv[t][r] = f2bf(p);
            }
        }

        #pragma unroll
        for (int c = 0; c < 2; ++c) {
            FragAB vf, pb;
            s16x4 v0 = *(const s16x4*)&vb[colL * 4096 + m0 + c * 32 + quad * 4];
            s16x4 v1 = *(const s16x4*)&vb[colL * 4096 + m0 + c * 32 + 16 + quad * 4];
            #pragma unroll
            for (int j = 0; j < 4; ++j) {
                vf.s[j]     = v0[j];
                vf.s[j + 4] = v1[j];
                pb.s[j]     = pv[c * 2][j];
                pb.s[j + 4] = pv[c * 2 + 1][j];
            }
            o_acc = __builtin_amdgcn_mfma_f32_16x16x32_bf16(vf.b, pb.b, o_acc, 0, 0, 0);
        }
    }

    // l: sum the 4 quads (lanes sharing colL = q)
    float l = l0 + l1;
    l += __shfl_xor(l, 16, 64);
    l += __shfl_xor(l, 32, 64);

    if (SPLIT > 1) {
        #pragma unroll
        for (int r = 0; r < 4; ++r)
            Opart[((s * 8 + h) * 16 + quad * 4 + r) * 4096 + q0 + colL] = o_acc[r];
        if (quad == 0) lpart[(s * 8 + h) * 4096 + q0 + colL] = l;
    } else {
        const float inv = 1.f / l;
        #pragma unroll
        for (int r = 0; r < 4; ++r)
            out[(h * 16 + quad * 4 + r) * 4096 + q0 + colL] = o_acc[r] * inv;
    }
}

// ---------------------------------------------------------------------------
__global__ __launch_bounds__(256) void combine_kernel(
    const float* __restrict__ Opart, const float* __restrict__ lpart,
    float* __restrict__ out)
{
    const int row = blockIdx.x >> 2;                       // 0..127 = h*16+d
    const int n   = (blockIdx.x & 3) * 1024 + threadIdx.x * 4;
    const int h   = row >> 4;
    f32x4 osum = {0.f, 0.f, 0.f, 0.f}, lsum = {0.f, 0.f, 0.f, 0.f};
    #pragma unroll
    for (int s = 0; s < 4; ++s) {
        osum += *(const f32x4*)&Opart[(s * 128 + row) * 4096 + n];
        lsum += *(const f32x4*)&lpart[(s * 8 + h) * 4096 + n];
    }
    f32x4 res;
    #pragma unroll
    for (int r = 0; r < 4; ++r) res[r] = osum[r] / lsum[r];
    *(f32x4*)&out[row * 4096 + n] = res;
}

// ---------------------------------------------------------------------------
extern "C" void kernel_launch(void* const* d_in, const int* in_sizes, int n_in,
                              void* d_out, int out_size, void* d_ws, size_t ws_size,
                              hipStream_t stream) {
    const float* x = (const float*)d_in[0];   // (128, 4096) fp32
    const float* w = (const float*)d_in[1];   // (384, 128) fp32
    float* out = (float*)d_out;               // (128, 4096) fp32

    char* ws = (char*)d_ws;
    short* qT = (short*)ws;                          // 1 MB
    short* kT = (short*)(ws + (1u << 20));           // 1 MB
    short* vv = (short*)(ws + (2u << 20));           // 1 MB

    const size_t opart_bytes = 4ull * 128 * 4096 * 4;   // 8 MB
    const size_t lpart_bytes = 4ull * 8 * 4096 * 4;     // 0.5 MB
    const size_t need_split  = (3ull << 20) + opart_bytes + lpart_bytes;

    dim3 gq(64, 4);
    qkv_kernel<<<gq, 256, 0, stream>>>(x, w, qT, kT, vv);

    if (ws_size >= need_split) {
        float* Opart = (float*)(ws + (3ull << 20));
        float* lpart = (float*)(ws + (3ull << 20) + opart_bytes);
        attn_kernel<4><<<2048, 256, 0, stream>>>(qT, kT, vv, Opart, lpart, out);
        combine_kernel<<<512, 256, 0, stream>>>(Opart, lpart, out);
    } else {
        attn_kernel<1><<<512, 256, 0, stream>>>(qT, kT, vv, nullptr, nullptr, out);
    }
}

// Round 6
// 142.207 us; speedup vs baseline: 1.4166x; 1.0099x over previous
//
#include <hip/hip_runtime.h>

// ---------------------------------------------------------------------------
// CMHSAttn v5: fp32 in/out. Identical to validated v4 except the softmax exp
// path: exp2f (OCML precise libcall, ~20+ VALU each — R5's 470 VALU/tile) is
// replaced by __expf (v_mul + v_exp_f32). Scale folded into qT is now plain
// 1/sqrt(128) (natural-log domain).
// ---------------------------------------------------------------------------

typedef __attribute__((ext_vector_type(4))) float  f32x4;
typedef __attribute__((ext_vector_type(8))) short  s16x8;
typedef __attribute__((ext_vector_type(4))) short  s16x4;
typedef __attribute__((ext_vector_type(8))) __bf16 bf16x8;

union FragAB { s16x8 s; bf16x8 b; };

__device__ __forceinline__ short f2bf(float f) {
    unsigned u = __float_as_uint(f);
    u += 0x7fff + ((u >> 16) & 1);          // RNE
    return (short)(u >> 16);
}

#define QSCALE 0.08838834764831845f   // 1/sqrt(128) (d_model, per reference)

// ---------------------------------------------------------------------------
// QKV: A = W-frag (fp32 load + cvt), B = X^T-frag (LDS-staged bf16).
// grid (64 n-tiles of 64, 4 o-quarters of 96), 256 thr. Wave = 16 n x 96 o.
// ---------------------------------------------------------------------------
__global__ __launch_bounds__(256) void qkv_kernel(
    const float* __restrict__ x, const float* __restrict__ w,
    short* __restrict__ qT, short* __restrict__ kT, short* __restrict__ v)
{
    __shared__ __align__(16) short xT[4][16][136];   // [wave][n][c], pad 8
    const int wv   = threadIdx.x >> 6;
    const int lane = threadIdx.x & 63;
    const int colL = lane & 15, quad = lane >> 4;
    const int n0 = blockIdx.x * 64 + wv * 16;
    const int oq = blockIdx.y;                        // 0..3

    // stage X^T slice: 16 n x 128 c per wave (fp32 -> bf16)
    #pragma unroll
    for (int rr = 0; rr < 4; ++rr) {
        int c  = rr * 32 + (lane >> 1);
        int nh = (lane & 1) * 8;
        f32x4 a = *(const f32x4*)&x[c * 4096 + n0 + nh];
        f32x4 b = *(const f32x4*)&x[c * 4096 + n0 + nh + 4];
        #pragma unroll
        for (int t = 0; t < 4; ++t) {
            xT[wv][nh + t][c]     = f2bf(a[t]);
            xT[wv][nh + 4 + t][c] = f2bf(b[t]);
        }
    }
    __syncthreads();

    FragAB xb[4];
    #pragma unroll
    for (int ks = 0; ks < 4; ++ks)
        xb[ks].s = *(const s16x8*)&xT[wv][colL][ks * 32 + quad * 8];

    #pragma unroll
    for (int i = 0; i < 6; ++i) {
        const int otg  = oq * 6 + i;          // global 16-o tile, 0..23
        const int ob   = otg * 16;
        const int h    = otg / 3;
        const int kind = otg % 3;             // 0=q, 1=k, 2=v
        f32x4 acc = {0.f, 0.f, 0.f, 0.f};
        #pragma unroll
        for (int ks = 0; ks < 4; ++ks) {
            f32x4 wa0 = *(const f32x4*)&w[(ob + colL) * 128 + ks * 32 + quad * 8];
            f32x4 wa1 = *(const f32x4*)&w[(ob + colL) * 128 + ks * 32 + quad * 8 + 4];
            FragAB wa;
            #pragma unroll
            for (int t = 0; t < 4; ++t) {
                wa.s[t]     = f2bf(wa0[t]);
                wa.s[t + 4] = f2bf(wa1[t]);
            }
            acc = __builtin_amdgcn_mfma_f32_16x16x32_bf16(wa.b, xb[ks].b, acc, 0, 0, 0);
        }
        // C: row = o_local = quad*4+r, col = n = n0+colL
        if (kind == 2) {
            #pragma unroll
            for (int r = 0; r < 4; ++r)
                v[(h * 16 + quad * 4 + r) * 4096 + n0 + colL] = f2bf(acc[r]);
        } else {
            short* dst = (kind == 0) ? qT : kT;
            const float sc = (kind == 0) ? QSCALE : 1.0f;
            s16x4 pk;
            #pragma unroll
            for (int r = 0; r < 4; ++r) pk[r] = f2bf(acc[r] * sc);
            *(s16x4*)&dst[(h * 4096 + n0 + colL) * 16 + quad * 4] = pk;
        }
    }
}

// ---------------------------------------------------------------------------
// Attention. Wave = 16 q rows x key chunk. Block = 4 waves. No LDS/barriers.
// S^T = K*Q^T: st[t][r] = score[key = m0+t*16+quad*4+r][q = q0+colL].
// PV: A = V (m=d), B = P^T with k-slot (quad,j) -> key m0+c*32+(j<4?0:16)
//     +quad*4+(j&3) -- exactly the lane's own st values.
// ---------------------------------------------------------------------------
template<int SPLIT>
__global__ __launch_bounds__(256) void attn_kernel(
    const short* __restrict__ qT, const short* __restrict__ kT,
    const short* __restrict__ v,
    float* __restrict__ Opart, float* __restrict__ lpart,
    float* __restrict__ out)
{
    const int wv   = threadIdx.x >> 6;
    const int lane = threadIdx.x & 63;
    const int colL = lane & 15, quad = lane >> 4;

    const int bx = blockIdx.x;
    int s, h, qt4;
    if (SPLIT > 1) { s = bx >> 9; h = (bx >> 6) & 7; qt4 = bx & 63; }
    else           { s = 0;       h = bx >> 6;       qt4 = bx & 63; }
    const int q0  = qt4 * 64 + wv * 16;
    const int nkt = 64 / SPLIT;

    const short* qb = qT + (h * 4096 + q0) * 16;
    const short* kb = kT +  h * 4096 * 16;
    const short* vb = v  +  h * 16 * 4096;

    FragAB qf; qf.s = 0;                       // B-frag: Q^T[d][q], d<16
    if (quad < 2) qf.s = *(const s16x8*)&qb[colL * 16 + quad * 8];

    f32x4 o_acc = {0.f, 0.f, 0.f, 0.f};        // C: row=d, col=q
    float l0 = 0.f, l1 = 0.f;

    const int kt_base = s * nkt;
    for (int kt = 0; kt < nkt; ++kt) {
        const int m0 = (kt_base + kt) * 64;

        FragAB kf[4];                           // A-frag: K[key][d], d<16
        #pragma unroll
        for (int t = 0; t < 4; ++t) {
            kf[t].s = 0;
            if (quad < 2)
                kf[t].s = *(const s16x8*)&kb[(m0 + t * 16 + colL) * 16 + quad * 8];
        }
        f32x4 st[4];
        #pragma unroll
        for (int t = 0; t < 4; ++t) {
            f32x4 z = {0.f, 0.f, 0.f, 0.f};
            st[t] = __builtin_amdgcn_mfma_f32_16x16x32_bf16(kf[t].b, qf.b, z, 0, 0, 0);
        }

        // fast exp (v_mul + v_exp_f32); clamp => finite everywhere, l > 0
        short pv[4][4];
        #pragma unroll
        for (int t = 0; t < 4; ++t) {
            #pragma unroll
            for (int r = 0; r < 4; ++r) {
                float sv = fminf(fmaxf(st[t][r], -20.f), 40.f);
                float p  = __expf(sv);
                if (r & 1) l1 += p; else l0 += p;
                pv[t][r] = f2bf(p);
            }
        }

        #pragma unroll
        for (int c = 0; c < 2; ++c) {
            FragAB vf, pb;
            s16x4 v0 = *(const s16x4*)&vb[colL * 4096 + m0 + c * 32 + quad * 4];
            s16x4 v1 = *(const s16x4*)&vb[colL * 4096 + m0 + c * 32 + 16 + quad * 4];
            #pragma unroll
            for (int j = 0; j < 4; ++j) {
                vf.s[j]     = v0[j];
                vf.s[j + 4] = v1[j];
                pb.s[j]     = pv[c * 2][j];
                pb.s[j + 4] = pv[c * 2 + 1][j];
            }
            o_acc = __builtin_amdgcn_mfma_f32_16x16x32_bf16(vf.b, pb.b, o_acc, 0, 0, 0);
        }
    }

    // l: sum the 4 quads (lanes sharing colL = q)
    float l = l0 + l1;
    l += __shfl_xor(l, 16, 64);
    l += __shfl_xor(l, 32, 64);

    if (SPLIT > 1) {
        #pragma unroll
        for (int r = 0; r < 4; ++r)
            Opart[((s * 8 + h) * 16 + quad * 4 + r) * 4096 + q0 + colL] = o_acc[r];
        if (quad == 0) lpart[(s * 8 + h) * 4096 + q0 + colL] = l;
    } else {
        const float inv = 1.f / l;
        #pragma unroll
        for (int r = 0; r < 4; ++r)
            out[(h * 16 + quad * 4 + r) * 4096 + q0 + colL] = o_acc[r] * inv;
    }
}

// ---------------------------------------------------------------------------
__global__ __launch_bounds__(256) void combine_kernel(
    const float* __restrict__ Opart, const float* __restrict__ lpart,
    float* __restrict__ out)
{
    const int row = blockIdx.x >> 2;                       // 0..127 = h*16+d
    const int n   = (blockIdx.x & 3) * 1024 + threadIdx.x * 4;
    const int h   = row >> 4;
    f32x4 osum = {0.f, 0.f, 0.f, 0.f}, lsum = {0.f, 0.f, 0.f, 0.f};
    #pragma unroll
    for (int s = 0; s < 4; ++s) {
        osum += *(const f32x4*)&Opart[(s * 128 + row) * 4096 + n];
        lsum += *(const f32x4*)&lpart[(s * 8 + h) * 4096 + n];
    }
    f32x4 res;
    #pragma unroll
    for (int r = 0; r < 4; ++r) res[r] = osum[r] / lsum[r];
    *(f32x4*)&out[row * 4096 + n] = res;
}

// ---------------------------------------------------------------------------
extern "C" void kernel_launch(void* const* d_in, const int* in_sizes, int n_in,
                              void* d_out, int out_size, void* d_ws, size_t ws_size,
                              hipStream_t stream) {
    const float* x = (const float*)d_in[0];   // (128, 4096) fp32
    const float* w = (const float*)d_in[1];   // (384, 128) fp32
    float* out = (float*)d_out;               // (128, 4096) fp32

    char* ws = (char*)d_ws;
    short* qT = (short*)ws;                          // 1 MB
    short* kT = (short*)(ws + (1u << 20));           // 1 MB
    short* vv = (short*)(ws + (2u << 20));           // 1 MB

    const size_t opart_bytes = 4ull * 128 * 4096 * 4;   // 8 MB
    const size_t lpart_bytes = 4ull * 8 * 4096 * 4;     // 0.5 MB
    const size_t need_split  = (3ull << 20) + opart_bytes + lpart_bytes;

    dim3 gq(64, 4);
    qkv_kernel<<<gq, 256, 0, stream>>>(x, w, qT, kT, vv);

    if (ws_size >= need_split) {
        float* Opart = (float*)(ws + (3ull << 20));
        float* lpart = (float*)(ws + (3ull << 20) + opart_bytes);
        attn_kernel<4><<<2048, 256, 0, stream>>>(qT, kT, vv, Opart, lpart, out);
        combine_kernel<<<512, 256, 0, stream>>>(Opart, lpart, out);
    } else {
        attn_kernel<1><<<512, 256, 0, stream>>>(qT, kT, vv, nullptr, nullptr, out);
    }
}